// Round 8
// baseline (33785.303 us; speedup 1.0000x reference)
//
#include <hip/hip_runtime.h>

#define GWG 256      // workgroups (1 per CU)
#define BTH 768      // threads per WG (12 waves)
#define WROW 2052    // LDS row pitch for Wih1 (bf16 elems): 2048 + 4 (bank de-alias)
#define LDSZ 111296
#define TB   0x5AB00001   // tag base: step t posts tag TB+t

typedef float f4v __attribute__((ext_vector_type(4)));

// ---------- helpers ----------
__device__ __forceinline__ unsigned short b16(float f) {   // f32 -> bf16 (RNE)
  union { float f; unsigned int i; } z; z.f = f;
  unsigned int r = z.i + 0x7fffu + ((z.i >> 16) & 1u);
  return (unsigned short)(r >> 16);
}
__device__ __forceinline__ float bup(unsigned short u) {
  union { unsigned int i; float f; } z; z.i = ((unsigned int)u) << 16; return z.f;
}
__device__ __forceinline__ float blo(unsigned int p) {
  union { unsigned int i; float f; } z; z.i = p << 16; return z.f;
}
__device__ __forceinline__ float bhi(unsigned int p) {
  union { unsigned int i; float f; } z; z.i = p & 0xffff0000u; return z.f;
}
__device__ __forceinline__ float sigm(float x) { return 1.f / (1.f + expf(-x)); }

__device__ __forceinline__ void stG(float* p2, f4v v) {
  asm volatile("global_store_dwordx4 %0, %1, off sc0 sc1" :: "v"(p2), "v"(v) : "memory");
}

// wave-0 batched gather: 64 lanes x 8 chunks (stride 64 chunks), bf16 payload -> LDS
__device__ __forceinline__ void pollH(const float* mb, int tag, unsigned short* lHb) {
  const int L = threadIdx.x;                 // caller guarantees < 64
  const float* base = mb + L * 4;
  f4v v[8];
  for (;;) {
#pragma unroll
    for (int s = 0; s < 8; ++s)
      asm volatile("global_load_dwordx4 %0, %1, off sc0 sc1"
                   : "=v"(v[s]) : "v"(base + s * 256) : "memory");
    asm volatile("s_waitcnt vmcnt(0)" ::: "memory");
    __builtin_amdgcn_sched_barrier(0);
    bool ok = true;
#pragma unroll
    for (int s = 0; s < 8; ++s) ok &= (__float_as_int(v[s][3]) == tag);
    if (__all(ok)) break;
    __builtin_amdgcn_s_sleep(1);
  }
#pragma unroll
  for (int s = 0; s < 8; ++s) {
    int c = s * 64 + L;
    uint2 u; u.x = __float_as_uint(v[s][0]); u.y = __float_as_uint(v[s][1]);
    *(uint2*)&lHb[c * 4] = u;                // 4 bf16 = 8B per chunk
  }
}
// wave-0 e-gather: 64 lanes x 4 chunks; payload = partial expsum; writes lse to LDS
__device__ __forceinline__ void pollE(const float* mb, int tag, float* lseSlot) {
  const int L = threadIdx.x;
  const float* base = mb + L * 4;
  f4v v[4];
  for (;;) {
#pragma unroll
    for (int s = 0; s < 4; ++s)
      asm volatile("global_load_dwordx4 %0, %1, off sc0 sc1"
                   : "=v"(v[s]) : "v"(base + s * 256) : "memory");
    asm volatile("s_waitcnt vmcnt(0)" ::: "memory");
    __builtin_amdgcn_sched_barrier(0);
    bool ok = true;
#pragma unroll
    for (int s = 0; s < 4; ++s) ok &= (__float_as_int(v[s][3]) == tag);
    if (__all(ok)) break;
    __builtin_amdgcn_s_sleep(1);
  }
  float s = v[0][0] + v[1][0] + v[2][0] + v[3][0];
#pragma unroll
  for (int d = 1; d < 64; d <<= 1) s += __shfl_xor(s, d);
  if (L == 0) *lseSlot = logf(s);
}

// ---------- pre-kernels ----------
__global__ __launch_bounds__(256) void prep(const float* __restrict__ bih0, const float* __restrict__ bhh0,
                                            const float* __restrict__ bih1, const float* __restrict__ bhh1,
                                            float* __restrict__ b0, float* __restrict__ b1f) {
  int i = blockIdx.x * 256 + threadIdx.x;
  if (i < 8192) { b0[i] = bih0[i] + bhh0[i]; b1f[i] = bih1[i] + bhh1[i]; }
}

__global__ __launch_bounds__(256) void transpose_wx(const float* __restrict__ Wih0, float* __restrict__ WxT) {
  int idx = blockIdx.x * 256 + threadIdx.x;          // 360*8192 total
  int r = idx & 8191, k = idx >> 13;
  WxT[(size_t)k * 8192 + r] = Wih0[(size_t)r * 424 + k];
}

// gates_x = inputVecs @ Wx^T + b0, bf16, COMPACT rows {i,g,o} -> [t][6144]
__global__ __launch_bounds__(256) void gemm_gx(const float* __restrict__ inV, const float* __restrict__ WxT,
                                               const float* __restrict__ b0, unsigned short* __restrict__ gxb) {
  __shared__ float lin[32 * 360];
  int t0 = blockIdx.x * 32;
  int by = blockIdx.y;                 // 0..23
  int ry = by >> 3;                    // 0,1,2  (compact gate)
  int gatey = ry + (ry ? 1 : 0);       // {0,2,3}
  int r  = gatey * 2048 + (by & 7) * 256 + threadIdx.x;   // original row (weights/bias)
  int cr = ry    * 2048 + (by & 7) * 256 + threadIdx.x;   // compact row (output)
  for (int i = threadIdx.x; i < 32 * 360; i += 256) lin[i] = inV[(size_t)t0 * 360 + i];
  __syncthreads();
  float b = b0[r];
  float acc[32];
#pragma unroll
  for (int tt = 0; tt < 32; ++tt) acc[tt] = b;
  for (int k = 0; k < 360; k += 4) {
    float w0 = WxT[(size_t)(k + 0) * 8192 + r];
    float w1 = WxT[(size_t)(k + 1) * 8192 + r];
    float w2 = WxT[(size_t)(k + 2) * 8192 + r];
    float w3 = WxT[(size_t)(k + 3) * 8192 + r];
#pragma unroll
    for (int tt = 0; tt < 32; ++tt) {
      float4 l = *reinterpret_cast<const float4*>(&lin[tt * 360 + k]);
      acc[tt] = fmaf(w0, l.x, fmaf(w1, l.y, fmaf(w2, l.z, fmaf(w3, l.w, acc[tt]))));
    }
  }
  for (int tt = 0; tt < 32; ++tt) gxb[(size_t)(t0 + tt) * 6144 + cr] = b16(acc[tt]);
}

// Wml = Wmap @ Wlin  [64 x 2048] f32
__global__ __launch_bounds__(256) void wml_k(const float* __restrict__ Wmap, const float* __restrict__ Wlin,
                                             float* __restrict__ wml) {
  __shared__ float lm[512];
  int e = blockIdx.x;                         // 0..63
  int k = blockIdx.y * 256 + threadIdx.x;     // 0..2047
  for (int i = threadIdx.x; i < 512; i += 256) lm[i] = Wmap[e * 512 + i];
  __syncthreads();
  float acc = 0.f;
  for (int c = 0; c < 512; ++c) acc = fmaf(lm[c], Wlin[(size_t)c * 2048 + k], acc);
  wml[(size_t)e * 2048 + k] = acc;
}

// Wbig = We @ Wml -> bf16, compact rows [6144 x 2048]
__global__ __launch_bounds__(256) void wbig_k(const float* __restrict__ Wih0, const float* __restrict__ wml,
                                              unsigned short* __restrict__ wbig) {
  __shared__ float lWe[32 * 64];
  int cr0 = blockIdx.x * 32;
  int c = blockIdx.y * 256 + threadIdx.x;
  for (int i = threadIdx.x; i < 32 * 64; i += 256) {
    int r2 = i >> 6, e = i & 63;
    int cr = cr0 + r2; int orig = cr + (cr >= 2048 ? 2048 : 0);
    lWe[i] = Wih0[(size_t)orig * 424 + 360 + e];
  }
  __syncthreads();
  float wr[64];
#pragma unroll
  for (int e = 0; e < 64; ++e) wr[e] = wml[(size_t)e * 2048 + c];
  for (int r2 = 0; r2 < 32; ++r2) {
    float acc = 0.f;
#pragma unroll
    for (int e = 0; e < 64; ++e) acc = fmaf(lWe[r2 * 64 + e], wr[e], acc);
    wbig[(size_t)(cr0 + r2) * 2048 + c] = b16(acc);
  }
}

// consts: rs = We@(Wmap@1); bc2 = We@(Wmap@blin + bmap); g0c = We@embed0   [compact 6144]
__global__ __launch_bounds__(256) void rsk(const float* __restrict__ Wih0, const float* __restrict__ Wmap,
                                           const float* __restrict__ blin, const float* __restrict__ bmap,
                                           const float* __restrict__ emb0,
                                           float* __restrict__ rs, float* __restrict__ bc2,
                                           float* __restrict__ g0c) {
  __shared__ float mrs[64], mu1[64];
  if (threadIdx.x < 64) {
    int e = threadIdx.x;
    float s = 0.f, u = 0.f;
    for (int c = 0; c < 512; ++c) {
      float wv = Wmap[e * 512 + c];
      s += wv; u = fmaf(wv, blin[c], u);
    }
    mrs[e] = s; mu1[e] = u + bmap[e];
  }
  __syncthreads();
  int cr = blockIdx.x * 256 + threadIdx.x;
  if (cr >= 6144) return;
  int orig = cr + (cr >= 2048 ? 2048 : 0);
  float a = 0.f, b = 0.f, g = 0.f;
  for (int e = 0; e < 64; ++e) {
    float w = Wih0[(size_t)orig * 424 + 360 + e];
    a = fmaf(w, mrs[e], a);
    b = fmaf(w, mu1[e], b);
    g = fmaf(w, emb0[e], g);
  }
  rs[cr] = a; bc2[cr] = b; g0c[cr] = g;
}

// ---------- persistent scan kernel ----------
struct KP {
  const float* Wih1; const float* Wlin; const float* blin; const float* b1f;
  const unsigned short* gxb; const unsigned short* wbig;
  const float* rs; const float* bc2; const float* g0c;
  float* mb_h0; float* mb_h1; float* mb_e;     // global tagged mailboxes
  float* out;
};

__global__ __launch_bounds__(BTH) void lstm_seq(KP p) {
  extern __shared__ __align__(16) char smem[];
  unsigned short* lW1 = (unsigned short*)smem;                  // 24 x WROW (Wih1 slice)  98,496
  unsigned short* lWl = (unsigned short*)(smem + 98496);        // 2 x 2048  (Wlin rows)    8,192
  unsigned short* lHb = (unsigned short*)(smem + 106688);       // 2048 bf16 (h gather)     4,096
  float* lRA = (float*)(smem + 110784);                         // 24 (A + gx + bc2)
  float* lRS = (float*)(smem + 110912);                         // 24 (rs, static)
  float* lR  = (float*)(smem + 111040);                         // 24 (layer-1 pre-acts)
  float* lV  = (float*)(smem + 111168);                         // 8
  float* lSe = (float*)(smem + 111232);                         // lse slot

  const int w = blockIdx.x, tid = threadIdx.x;
  const int rl = tid >> 5;          // 0..23 gate-row
  const int l32 = tid & 31;
  const int g3 = rl >> 3;                   // 0,1,2 (i,g,o compact)
  const int gate = g3 + (g3 ? 1 : 0);       // {0,2,3} original layout
  const int gr  = w * 8 + (rl & 7) + 2048 * gate;   // original-space (Wih1, b1f)
  const int crt = w * 8 + (rl & 7) + 2048 * g3;     // compact (gxb, wbig, rs, bc2, g0c)

  // ---- stage weights into LDS (once) ----
  for (int r2 = 0; r2 < 24; ++r2) {
    int gg = r2 >> 3; int grr = w * 8 + (r2 & 7) + 2048 * (gg + (gg ? 1 : 0));
    const float* src = p.Wih1 + (size_t)grr * 2048;
    for (int i = tid; i < 2048; i += BTH) lW1[r2 * WROW + i] = b16(src[i]);
  }
  for (int i = tid; i < 2 * 2048; i += BTH) {
    int q = i >> 11, k = i & 2047;
    lWl[i] = b16(p.Wlin[(size_t)(w * 2 + q) * 2048 + k]);
  }
  const float b1r  = p.b1f[gr];
  const float rs_r = p.rs[crt], bc2_r = p.bc2[crt], g0_r = p.g0c[crt];
  const float bl0 = p.blin[w * 2], bl1 = p.blin[w * 2 + 1];
  unsigned short gxu = p.gxb[crt];                 // gx for t=0
  if (l32 == 0) lRS[rl] = rs_r;
  const unsigned short* wbr = p.wbig + (size_t)crt * 2048;
  __syncthreads();

  for (int t = 0; t < 4096; ++t) {
    const int tagt = TB + t;
    const unsigned short gxu_n = p.gxb[(size_t)(t < 4095 ? t + 1 : t) * 6144 + crt];
    // ============ phase 1: fold A = Wbig@h1(t-1)  [hides e-hop], poll e, cell h0 ============
    if (t > 0) {
      float acc = 0.f;
#pragma unroll 4
      for (int mm = 0; mm < 16; ++mm) {
        int k = l32 * 4 + mm * 128;
        ushort4 uw = *(const ushort4*)&wbr[k];     // global (L2-hot, plain cached load)
        ushort4 uh = *(const ushort4*)&lHb[k];     // h1(t-1)
        acc = fmaf(bup(uw.x), bup(uh.x), acc);
        acc = fmaf(bup(uw.y), bup(uh.y), acc);
        acc = fmaf(bup(uw.z), bup(uh.z), acc);
        acc = fmaf(bup(uw.w), bup(uh.w), acc);
      }
      acc += __shfl_xor(acc, 1); acc += __shfl_xor(acc, 2); acc += __shfl_xor(acc, 4);
      acc += __shfl_xor(acc, 8); acc += __shfl_xor(acc, 16);
      if (l32 == 0) lRA[rl] = acc + bup(gxu) + bc2_r;
      if (tid < 64) pollE(p.mb_e, tagt - 1, lSe);      // wave0: gather partial expsums -> lse
    } else {
      if (l32 == 0) lRA[rl] = bup(gxu) + g0_r;
      if (tid == 0) lSe[0] = 0.f;
    }
    __syncthreads();                                           // S_b
    // cell -> h0 (wave0 lanes 0..7), shuffle-pack, post
    if (tid < 8) {
      float ls = lSe[0];
      float pi = lRA[tid]      - ls * lRS[tid];
      float pg = lRA[8 + tid]  - ls * lRS[8 + tid];
      float po = lRA[16 + tid] - ls * lRS[16 + tid];
      float cc = sigm(pi) * tanhf(pg);
      float h  = sigm(po) * tanhf(cc);
      unsigned hb = (unsigned)b16(h);
      unsigned a0 = __shfl(hb, tid * 4 + 0);
      unsigned a1 = __shfl(hb, tid * 4 + 1);
      unsigned a2 = __shfl(hb, tid * 4 + 2);
      unsigned a3 = __shfl(hb, tid * 4 + 3);
      if (tid < 2) {
        f4v c;
        c[0] = __uint_as_float(a0 | (a1 << 16));
        c[1] = __uint_as_float(a2 | (a3 << 16));
        c[2] = 0.f; c[3] = __int_as_float(tagt);
        stG(p.mb_h0 + w * 8 + tid * 4, c);
      }
    }
    // ============ phase 2: gather h0 [wave0], Wih1 matvec ============
    if (tid < 64) pollH(p.mb_h0, tagt, lHb);
    __syncthreads();                                           // S_c
    {
      float acc = 0.f;
      const unsigned short* wr = lW1 + rl * WROW;
#pragma unroll 4
      for (int mm = 0; mm < 16; ++mm) {
        int k = l32 * 4 + mm * 128;
        ushort4 uw = *(const ushort4*)&wr[k];
        ushort4 uh = *(const ushort4*)&lHb[k];
        acc = fmaf(bup(uw.x), bup(uh.x), acc);
        acc = fmaf(bup(uw.y), bup(uh.y), acc);
        acc = fmaf(bup(uw.z), bup(uh.z), acc);
        acc = fmaf(bup(uw.w), bup(uh.w), acc);
      }
      acc += __shfl_xor(acc, 1); acc += __shfl_xor(acc, 2); acc += __shfl_xor(acc, 4);
      acc += __shfl_xor(acc, 8); acc += __shfl_xor(acc, 16);
      if (l32 == 0) lR[rl] = acc + b1r;
    }
    __syncthreads();                                           // S_d
    // cell -> h1 (wave0), post
    if (tid < 8) {
      float cc = sigm(lR[tid]) * tanhf(lR[8 + tid]);
      float h  = sigm(lR[16 + tid]) * tanhf(cc);
      unsigned hb = (unsigned)b16(h);
      unsigned a0 = __shfl(hb, tid * 4 + 0);
      unsigned a1 = __shfl(hb, tid * 4 + 1);
      unsigned a2 = __shfl(hb, tid * 4 + 2);
      unsigned a3 = __shfl(hb, tid * 4 + 3);
      if (tid < 2) {
        f4v c;
        c[0] = __uint_as_float(a0 | (a1 << 16));
        c[1] = __uint_as_float(a2 | (a3 << 16));
        c[2] = 0.f; c[3] = __int_as_float(tagt);
        stG(p.mb_h1 + w * 8 + tid * 4, c);
      }
    }
    // ============ phase 3: gather h1 [wave0], own y rows, post e ============
    if (tid < 64) pollH(p.mb_h1, tagt, lHb);
    __syncthreads();                                           // S_e
    if (tid < 512) {
      int q = tid >> 8, l = tid & 255;
      float a = 0.f;
#pragma unroll
      for (int it = 0; it < 2; ++it) {
        int k = it * 1024 + l * 4;
        ushort4 uw = *(const ushort4*)&lWl[q * 2048 + k];
        ushort4 uh = *(const ushort4*)&lHb[k];
        a = fmaf(bup(uw.x), bup(uh.x), a);
        a = fmaf(bup(uw.y), bup(uh.y), a);
        a = fmaf(bup(uw.z), bup(uh.z), a);
        a = fmaf(bup(uw.w), bup(uh.w), a);
      }
#pragma unroll
      for (int d = 1; d < 64; d <<= 1) a += __shfl_xor(a, d);
      if ((tid & 63) == 0) lV[tid >> 6] = a;
    }
    __syncthreads();                                           // S_f
    if (tid == 0) {
      float y0 = lV[0] + lV[1] + lV[2] + lV[3] + bl0;
      float y1 = lV[4] + lV[5] + lV[6] + lV[7] + bl1;
      p.out[(size_t)t * 512 + w * 2]     = y0;
      p.out[(size_t)t * 512 + w * 2 + 1] = y1;
      f4v c; c[0] = expf(y0) + expf(y1); c[1] = 0.f; c[2] = 0.f; c[3] = __int_as_float(tagt);
      stG(p.mb_e + w * 4, c);
    }
    gxu = gxu_n;
  }
}

// ---------- host ----------
extern "C" void kernel_launch(void* const* d_in, const int* in_sizes, int n_in,
                              void* d_out, int out_size, void* d_ws, size_t ws_size,
                              hipStream_t stream) {
  const float* inV  = (const float*)d_in[0];
  const float* Wih0 = (const float*)d_in[1];
  const float* bih0 = (const float*)d_in[2];
  const float* bhh0 = (const float*)d_in[3];
  const float* Wih1 = (const float*)d_in[4];
  const float* bih1 = (const float*)d_in[5];
  const float* bhh1 = (const float*)d_in[6];
  const float* Wlin = (const float*)d_in[7];
  const float* blin = (const float*)d_in[8];
  const float* Wmap = (const float*)d_in[9];
  const float* bmap = (const float*)d_in[10];
  const float* emb0 = (const float*)d_in[11];

  char* ws = (char*)d_ws;
  unsigned short* gxb  = (unsigned short*)(ws);              // 4096*6144*2 = 50,331,648
  float*          WxT  = (float*)(ws + 50331648);            // 11,796,480 (dead after gemm_gx)
  unsigned short* wbig = (unsigned short*)(ws + 50331648);   // 25,165,824 (aliases WxT, written after)
  float* wml   = (float*)(ws + 75497472);                    // 64*2048*4 = 524,288
  float* b0    = (float*)(ws + 76021760);                    // 32 KB
  float* b1f   = (float*)(ws + 76054528);                    // 32 KB
  float* mb_h0 = (float*)(ws + 76087296);                    // 8 KB (512 x 16B)
  float* mb_h1 = (float*)(ws + 76095488);                    // 8 KB
  float* mb_e  = (float*)(ws + 76103680);                    // 4 KB (256 x 16B)
  float* rs    = (float*)(ws + 76107776);                    // 24 KB
  float* bc2   = (float*)(ws + 76132352);                    // 24 KB
  float* g0c   = (float*)(ws + 76156928);                    // 24 KB
  float* out   = (float*)d_out;

  prep<<<32, 256, 0, stream>>>(bih0, bhh0, bih1, bhh1, b0, b1f);
  transpose_wx<<<11520, 256, 0, stream>>>(Wih0, WxT);
  gemm_gx<<<dim3(128, 24), 256, 0, stream>>>(inV, WxT, b0, gxb);
  wml_k<<<dim3(64, 8), 256, 0, stream>>>(Wmap, Wlin, wml);
  wbig_k<<<dim3(192, 8), 256, 0, stream>>>(Wih0, wml, wbig);   // overwrites WxT region (now dead)
  rsk<<<24, 256, 0, stream>>>(Wih0, Wmap, blin, bmap, emb0, rs, bc2, g0c);

  hipFuncSetAttribute(reinterpret_cast<const void*>(lstm_seq),
                      hipFuncAttributeMaxDynamicSharedMemorySize, LDSZ);
  KP p{Wih1, Wlin, blin, b1f, gxb, wbig, rs, bc2, g0c, mb_h0, mb_h1, mb_e, out};
  void* args[] = { (void*)&p };
  hipError_t e = hipLaunchCooperativeKernel(reinterpret_cast<void*>(&lstm_seq),
                                            dim3(GWG), dim3(BTH), args, LDSZ, stream);
  if (e != hipSuccess) {
    lstm_seq<<<GWG, BTH, LDSZ, stream>>>(p);
  }
}

// Round 9
// 31250.415 us; speedup vs baseline: 1.0811x; 1.0811x over previous
//
#include <hip/hip_runtime.h>

#define GWG 256      // workgroups (1 per CU)
#define BTH 768      // threads per WG (12 waves)
#define WROW 2052    // LDS row pitch for Wih1 (bf16 elems)
#define LDSZ 137856
#define TB   0x5AB00001   // tag base: step t posts tag TB+t

typedef float f4v __attribute__((ext_vector_type(4)));

// ---------- helpers ----------
__device__ __forceinline__ unsigned short b16(float f) {   // f32 -> bf16 (RNE)
  union { float f; unsigned int i; } z; z.f = f;
  unsigned int r = z.i + 0x7fffu + ((z.i >> 16) & 1u);
  return (unsigned short)(r >> 16);
}
__device__ __forceinline__ float bup(unsigned short u) {
  union { unsigned int i; float f; } z; z.i = ((unsigned int)u) << 16; return z.f;
}
__device__ __forceinline__ float blo(unsigned int p) {
  union { unsigned int i; float f; } z; z.i = p << 16; return z.f;
}
__device__ __forceinline__ float bhi(unsigned int p) {
  union { unsigned int i; float f; } z; z.i = p & 0xffff0000u; return z.f;
}
__device__ __forceinline__ float sigm(float x) { return 1.f / (1.f + expf(-x)); }

__device__ __forceinline__ void stG(float* p2, f4v v) {
  asm volatile("global_store_dwordx4 %0, %1, off sc0 sc1" :: "v"(p2), "v"(v) : "memory");
}

// wave-0 batched gather from THIS consumer's replica: 64 lanes x 8 chunks -> LDS (bf16 payload)
__device__ __forceinline__ void pollH(const float* mb, int tag, unsigned short* lHb) {
  const int L = threadIdx.x;                 // caller guarantees < 64
  const float* base = mb + L * 4;
  f4v v[8];
  for (;;) {
#pragma unroll
    for (int s = 0; s < 8; ++s)
      asm volatile("global_load_dwordx4 %0, %1, off sc0 sc1"
                   : "=v"(v[s]) : "v"(base + s * 256) : "memory");
    asm volatile("s_waitcnt vmcnt(0)" ::: "memory");
    __builtin_amdgcn_sched_barrier(0);
    bool ok = true;
#pragma unroll
    for (int s = 0; s < 8; ++s) ok &= (__float_as_int(v[s][3]) == tag);
    if (__all(ok)) break;
    __builtin_amdgcn_s_sleep(1);
  }
#pragma unroll
  for (int s = 0; s < 8; ++s) {
    int c = s * 64 + L;
    uint2 u; u.x = __float_as_uint(v[s][0]); u.y = __float_as_uint(v[s][1]);
    *(uint2*)&lHb[c * 4] = u;                // 4 bf16 = 8B per chunk
  }
}

// ---------- pre-kernels ----------
__global__ __launch_bounds__(256) void prep(const float* __restrict__ bih0, const float* __restrict__ bhh0,
                                            const float* __restrict__ bih1, const float* __restrict__ bhh1,
                                            float* __restrict__ b0, float* __restrict__ b1f) {
  int i = blockIdx.x * 256 + threadIdx.x;
  if (i < 8192) { b0[i] = bih0[i] + bhh0[i]; b1f[i] = bih1[i] + bhh1[i]; }
}

__global__ __launch_bounds__(256) void transpose_wx(const float* __restrict__ Wih0, float* __restrict__ WxT) {
  int idx = blockIdx.x * 256 + threadIdx.x;          // 360*8192 total
  int r = idx & 8191, k = idx >> 13;
  WxT[(size_t)k * 8192 + r] = Wih0[(size_t)r * 424 + k];
}

// gates_x = inputVecs @ Wx^T + b0, bf16, COMPACT rows {i,g,o} -> [t][6144]
__global__ __launch_bounds__(256) void gemm_gx(const float* __restrict__ inV, const float* __restrict__ WxT,
                                               const float* __restrict__ b0, unsigned short* __restrict__ gxb) {
  __shared__ float lin[32 * 360];
  int t0 = blockIdx.x * 32;
  int by = blockIdx.y;                 // 0..23
  int ry = by >> 3;                    // 0,1,2  (compact gate)
  int gatey = ry + (ry ? 1 : 0);       // {0,2,3}
  int r  = gatey * 2048 + (by & 7) * 256 + threadIdx.x;   // original row (weights/bias)
  int cr = ry    * 2048 + (by & 7) * 256 + threadIdx.x;   // compact row (output)
  for (int i = threadIdx.x; i < 32 * 360; i += 256) lin[i] = inV[(size_t)t0 * 360 + i];
  __syncthreads();
  float b = b0[r];
  float acc[32];
#pragma unroll
  for (int tt = 0; tt < 32; ++tt) acc[tt] = b;
  for (int k = 0; k < 360; k += 4) {
    float w0 = WxT[(size_t)(k + 0) * 8192 + r];
    float w1 = WxT[(size_t)(k + 1) * 8192 + r];
    float w2 = WxT[(size_t)(k + 2) * 8192 + r];
    float w3 = WxT[(size_t)(k + 3) * 8192 + r];
#pragma unroll
    for (int tt = 0; tt < 32; ++tt) {
      float4 l = *reinterpret_cast<const float4*>(&lin[tt * 360 + k]);
      acc[tt] = fmaf(w0, l.x, fmaf(w1, l.y, fmaf(w2, l.z, fmaf(w3, l.w, acc[tt]))));
    }
  }
  for (int tt = 0; tt < 32; ++tt) gxb[(size_t)(t0 + tt) * 6144 + cr] = b16(acc[tt]);
}

// Wcomb = We @ Wmap, compact igo rows [6144][512], bf16
__global__ __launch_bounds__(256) void wcomb_k(const float* __restrict__ Wih0, const float* __restrict__ Wmap,
                                               unsigned short* __restrict__ wcomb) {
  __shared__ float lwe[64];
  int cr = blockIdx.x;                               // compact row 0..6143
  int orig = cr + (cr >= 2048 ? 2048 : 0);           // gate {0,2,3}
  if (threadIdx.x < 64) lwe[threadIdx.x] = Wih0[(size_t)orig * 424 + 360 + threadIdx.x];
  __syncthreads();
  int c = threadIdx.x;
  float a0 = 0.f, a1 = 0.f;
  for (int e = 0; e < 64; ++e) {
    float w = lwe[e];
    a0 = fmaf(w, Wmap[e * 512 + c], a0);
    a1 = fmaf(w, Wmap[e * 512 + c + 256], a1);
  }
  wcomb[(size_t)cr * 512 + c] = b16(a0);
  wcomb[(size_t)cr * 512 + c + 256] = b16(a1);
}

// rs = rowsum(Wcomb_bf16); bcomb = We@bmap; g0c = We@embed0   (compact [6144])
__global__ __launch_bounds__(256) void rsk(const unsigned short* __restrict__ wcomb,
                                           const float* __restrict__ Wih0,
                                           const float* __restrict__ bmap, const float* __restrict__ emb0,
                                           float* __restrict__ rs, float* __restrict__ bcomb,
                                           float* __restrict__ g0c) {
  int cr = blockIdx.x * 256 + threadIdx.x;
  if (cr >= 6144) return;
  int orig = cr + (cr >= 2048 ? 2048 : 0);
  float s = 0.f;
  for (int k = 0; k < 512; ++k) s += bup(wcomb[(size_t)cr * 512 + k]);
  float bc = 0.f, g0 = 0.f;
  for (int e = 0; e < 64; ++e) {
    float w = Wih0[(size_t)orig * 424 + 360 + e];
    bc = fmaf(w, bmap[e], bc);
    g0 = fmaf(w, emb0[e], g0);
  }
  rs[cr] = s; bcomb[cr] = bc; g0c[cr] = g0;
}

// ---------- persistent scan kernel ----------
struct KP {
  const float* Wih1; const float* Wlin; const float* blin; const float* b1f;
  const unsigned short* gxb; const unsigned short* wcomb;
  const float* rs; const float* bcomb; const float* g0c;
  float* mb_h0; float* mb_h1; float* mb_y;     // 8-replica tagged mailboxes
  float* out;
};

__global__ __launch_bounds__(BTH) void lstm_seq(KP p) {
  extern __shared__ __align__(16) char smem[];
  unsigned short* lW1  = (unsigned short*)smem;                 // 24 x WROW (Wih1 slice)  98,496
  unsigned short* lWl  = (unsigned short*)(smem + 98496);       // 2 x 2048  (Wlin rows)    8,192
  unsigned short* lWcb = (unsigned short*)(smem + 106688);      // 24 x 512  (Wcomb slice) 24,576
  unsigned short* lHb  = (unsigned short*)(smem + 131264);      // 2048 bf16 (h gather)     4,096
  float* lY  = (float*)(smem + 135360);                         // 512
  float* lRA = (float*)(smem + 137408);                         // 24 (fold + gx + bc)
  float* lRS = (float*)(smem + 137536);                         // 24 (rs, static)
  float* lR  = (float*)(smem + 137664);                         // 24 (layer-1 pre-acts)
  float* lV  = (float*)(smem + 137792);                         // 8

  const int w = blockIdx.x, tid = threadIdx.x;
  const int rl = tid >> 5;          // 0..23 gate-row
  const int l32 = tid & 31;
  const int g3 = rl >> 3;                   // 0,1,2 (i,g,o compact)
  const int gate = g3 + (g3 ? 1 : 0);       // {0,2,3} original layout
  const int gr  = w * 8 + (rl & 7) + 2048 * gate;   // original-space (Wih1, b1f)
  const int crt = w * 8 + (rl & 7) + 2048 * g3;     // compact (gxb, wcomb, rs, bcomb, g0c)
  const int rep = w & 7;                            // this consumer's replica

  // ---- stage weights into LDS (once) ----
  for (int r2 = 0; r2 < 24; ++r2) {
    int gg = r2 >> 3; int grr = w * 8 + (r2 & 7) + 2048 * (gg + (gg ? 1 : 0));
    const float* src = p.Wih1 + (size_t)grr * 2048;
    for (int i = tid; i < 2048; i += BTH) lW1[r2 * WROW + i] = b16(src[i]);
  }
  for (int i = tid; i < 24 * 512; i += BTH) {
    int r2 = i >> 9, k = i & 511;
    int crr = w * 8 + (r2 & 7) + 2048 * (r2 >> 3);
    lWcb[r2 * 512 + k] = p.wcomb[(size_t)crr * 512 + k];
  }
  for (int i = tid; i < 2 * 2048; i += BTH) {
    int q = i >> 11, k = i & 2047;
    lWl[i] = b16(p.Wlin[(size_t)(w * 2 + q) * 2048 + k]);
  }
  const float b1r  = p.b1f[gr];
  const float rs_r = p.rs[crt], bc_r = p.bcomb[crt], g0_r = p.g0c[crt];
  const float bl0 = p.blin[w * 2], bl1 = p.blin[w * 2 + 1];
  unsigned short gxu = p.gxb[crt];                 // gx for t=0
  if (l32 == 0) lRS[rl] = rs_r;
  __syncthreads();

  for (int t = 0; t < 4096; ++t) {
    const int tagt = TB + t;
    const unsigned short gxu_n = p.gxb[(size_t)(t < 4095 ? t + 1 : t) * 6144 + crt];
    float lse = 0.f;                                // valid in wave 0
    // ============ phase 1: gather y(t-1) [wave0], lse in-reg, Wcomb fold ============
    if (t > 0) {
      f4v yv[4];
      if (tid < 64) {
        const float* base = p.mb_y + rep * 1024 + tid * 4;
        for (;;) {
#pragma unroll
          for (int s = 0; s < 4; ++s)
            asm volatile("global_load_dwordx4 %0, %1, off sc0 sc1"
                         : "=v"(yv[s]) : "v"(base + s * 256) : "memory");
          asm volatile("s_waitcnt vmcnt(0)" ::: "memory");
          __builtin_amdgcn_sched_barrier(0);
          bool ok = true;
#pragma unroll
          for (int s = 0; s < 4; ++s) ok &= (__float_as_int(yv[s][3]) == tagt - 1);
          if (__all(ok)) break;
          __builtin_amdgcn_s_sleep(1);
        }
#pragma unroll
        for (int s = 0; s < 4; ++s) {
          int c = s * 64 + tid;
          lY[c * 2] = yv[s][0]; lY[c * 2 + 1] = yv[s][1];
        }
      }
      __syncthreads();                                         // S1
      if (tid < 64) {                  // lse from registers, overlapped with folds below
        float s = 0.f;
#pragma unroll
        for (int q = 0; q < 4; ++q) s += expf(yv[q][0]) + expf(yv[q][1]);
#pragma unroll
        for (int d = 1; d < 64; d <<= 1) s += __shfl_xor(s, d);
        lse = logf(s);
      }
      // Wcomb fold (all 24 rows, 12 waves)
      float acc = 0.f;
#pragma unroll
      for (int j = 0; j < 8; ++j) {
        int k = 2 * l32 + 64 * j;
        unsigned uwp = *(const unsigned*)&lWcb[rl * 512 + k];
        float2 yv2 = *(const float2*)&lY[k];
        acc = fmaf(blo(uwp), yv2.x, fmaf(bhi(uwp), yv2.y, acc));
      }
      acc += __shfl_xor(acc, 1); acc += __shfl_xor(acc, 2); acc += __shfl_xor(acc, 4);
      acc += __shfl_xor(acc, 8); acc += __shfl_xor(acc, 16);
      if (l32 == 0) lRA[rl] = bup(gxu) + acc + bc_r;
    } else {
      if (l32 == 0) lRA[rl] = bup(gxu) + g0_r;
    }
    __syncthreads();                                           // S3
    // wave0: cell -> h0 (lanes 0-7), pack, post to 8 replicas (lanes 0-15)
    if (tid < 16) {
      unsigned hb = 0u;
      if (tid < 8) {
        float pi = lRA[tid]      - lse * lRS[tid];
        float pg = lRA[8 + tid]  - lse * lRS[8 + tid];
        float po = lRA[16 + tid] - lse * lRS[16 + tid];
        float cc = sigm(pi) * tanhf(pg);
        hb = (unsigned)b16(sigm(po) * tanhf(cc));
      }
      int cpar = tid & 1;
      unsigned a0 = __shfl(hb, cpar * 4 + 0);
      unsigned a1 = __shfl(hb, cpar * 4 + 1);
      unsigned a2 = __shfl(hb, cpar * 4 + 2);
      unsigned a3 = __shfl(hb, cpar * 4 + 3);
      f4v c;
      c[0] = __uint_as_float(a0 | (a1 << 16));
      c[1] = __uint_as_float(a2 | (a3 << 16));
      c[2] = 0.f; c[3] = __int_as_float(tagt);
      stG(p.mb_h0 + (tid >> 1) * 2048 + (w * 2 + cpar) * 4, c);
    }
    // ============ phase 2: gather h0 [wave0], Wih1 matvec ============
    if (tid < 64) pollH(p.mb_h0 + rep * 2048, tagt, lHb);
    __syncthreads();                                           // S5
    {
      float acc = 0.f;
      const unsigned short* wr = lW1 + rl * WROW;
#pragma unroll 4
      for (int mm = 0; mm < 16; ++mm) {
        int k = l32 * 4 + mm * 128;
        ushort4 uw = *(const ushort4*)&wr[k];
        ushort4 uh = *(const ushort4*)&lHb[k];
        acc = fmaf(bup(uw.x), bup(uh.x), acc);
        acc = fmaf(bup(uw.y), bup(uh.y), acc);
        acc = fmaf(bup(uw.z), bup(uh.z), acc);
        acc = fmaf(bup(uw.w), bup(uh.w), acc);
      }
      acc += __shfl_xor(acc, 1); acc += __shfl_xor(acc, 2); acc += __shfl_xor(acc, 4);
      acc += __shfl_xor(acc, 8); acc += __shfl_xor(acc, 16);
      if (l32 == 0) lR[rl] = acc + b1r;
    }
    __syncthreads();                                           // S6
    // wave0: cell -> h1, post to 8 replicas
    if (tid < 16) {
      unsigned hb = 0u;
      if (tid < 8) {
        float cc = sigm(lR[tid]) * tanhf(lR[8 + tid]);
        hb = (unsigned)b16(sigm(lR[16 + tid]) * tanhf(cc));
      }
      int cpar = tid & 1;
      unsigned a0 = __shfl(hb, cpar * 4 + 0);
      unsigned a1 = __shfl(hb, cpar * 4 + 1);
      unsigned a2 = __shfl(hb, cpar * 4 + 2);
      unsigned a3 = __shfl(hb, cpar * 4 + 3);
      f4v c;
      c[0] = __uint_as_float(a0 | (a1 << 16));
      c[1] = __uint_as_float(a2 | (a3 << 16));
      c[2] = 0.f; c[3] = __int_as_float(tagt);
      stG(p.mb_h1 + (tid >> 1) * 2048 + (w * 2 + cpar) * 4, c);
    }
    // ============ phase 3: gather h1 [wave0], y rows, post y to 8 replicas ============
    if (tid < 64) pollH(p.mb_h1 + rep * 2048, tagt, lHb);
    __syncthreads();                                           // S8
    if (tid < 512) {
      int q = tid >> 8, l = tid & 255;
      float a = 0.f;
#pragma unroll
      for (int it = 0; it < 2; ++it) {
        int k = it * 1024 + l * 4;
        ushort4 uw = *(const ushort4*)&lWl[q * 2048 + k];
        ushort4 uh = *(const ushort4*)&lHb[k];
        a = fmaf(bup(uw.x), bup(uh.x), a);
        a = fmaf(bup(uw.y), bup(uh.y), a);
        a = fmaf(bup(uw.z), bup(uh.z), a);
        a = fmaf(bup(uw.w), bup(uh.w), a);
      }
#pragma unroll
      for (int d = 1; d < 64; d <<= 1) a += __shfl_xor(a, d);
      if ((tid & 63) == 0) lV[tid >> 6] = a;
    }
    __syncthreads();                                           // S9
    if (tid < 8) {
      float y0 = lV[0] + lV[1] + lV[2] + lV[3] + bl0;
      float y1 = lV[4] + lV[5] + lV[6] + lV[7] + bl1;
      f4v c; c[0] = y0; c[1] = y1; c[2] = 0.f; c[3] = __int_as_float(tagt);
      stG(p.mb_y + tid * 1024 + w * 4, c);
      if (tid == 0) {
        p.out[(size_t)t * 512 + w * 2]     = y0;
        p.out[(size_t)t * 512 + w * 2 + 1] = y1;
      }
    }
    gxu = gxu_n;
  }
}

// ---------- host ----------
extern "C" void kernel_launch(void* const* d_in, const int* in_sizes, int n_in,
                              void* d_out, int out_size, void* d_ws, size_t ws_size,
                              hipStream_t stream) {
  const float* inV  = (const float*)d_in[0];
  const float* Wih0 = (const float*)d_in[1];
  const float* bih0 = (const float*)d_in[2];
  const float* bhh0 = (const float*)d_in[3];
  const float* Wih1 = (const float*)d_in[4];
  const float* bih1 = (const float*)d_in[5];
  const float* bhh1 = (const float*)d_in[6];
  const float* Wlin = (const float*)d_in[7];
  const float* blin = (const float*)d_in[8];
  const float* Wmap = (const float*)d_in[9];
  const float* bmap = (const float*)d_in[10];
  const float* emb0 = (const float*)d_in[11];

  char* ws = (char*)d_ws;
  unsigned short* gxb   = (unsigned short*)(ws);             // 4096*6144*2 = 50,331,648
  float*          WxT   = (float*)(ws + 50331648);           // 11,796,480 (dead after gemm_gx)
  unsigned short* wcomb = (unsigned short*)(ws + 50331648);  // 6,291,456 (aliases WxT, written after)
  float* b0    = (float*)(ws + 62128128);                    // 32 KB
  float* b1f   = (float*)(ws + 62160896);                    // 32 KB
  float* mb_h0 = (float*)(ws + 62193664);                    // 64 KB (8 replicas x 512 x 16B)
  float* mb_h1 = (float*)(ws + 62259200);                    // 64 KB
  float* mb_y  = (float*)(ws + 62324736);                    // 32 KB (8 replicas x 256 x 16B)
  float* rs    = (float*)(ws + 62357504);                    // 24 KB
  float* bcomb = (float*)(ws + 62382080);                    // 24 KB
  float* g0c   = (float*)(ws + 62406656);                    // 24 KB
  float* out   = (float*)d_out;

  prep<<<32, 256, 0, stream>>>(bih0, bhh0, bih1, bhh1, b0, b1f);
  transpose_wx<<<11520, 256, 0, stream>>>(Wih0, WxT);
  gemm_gx<<<dim3(128, 24), 256, 0, stream>>>(inV, WxT, b0, gxb);
  wcomb_k<<<6144, 256, 0, stream>>>(Wih0, Wmap, wcomb);      // overwrites WxT region (now dead)
  rsk<<<24, 256, 0, stream>>>(wcomb, Wih0, bmap, emb0, rs, bcomb, g0c);

  hipFuncSetAttribute(reinterpret_cast<const void*>(lstm_seq),
                      hipFuncAttributeMaxDynamicSharedMemorySize, LDSZ);
  KP p{Wih1, Wlin, blin, b1f, gxb, wcomb, rs, bcomb, g0c, mb_h0, mb_h1, mb_y, out};
  void* args[] = { (void*)&p };
  hipError_t e = hipLaunchCooperativeKernel(reinterpret_cast<void*>(&lstm_seq),
                                            dim3(GWG), dim3(BTH), args, LDSZ, stream);
  if (e != hipSuccess) {
    lstm_seq<<<GWG, BTH, LDSZ, stream>>>(p);
  }
}

// Round 10
// 31055.820 us; speedup vs baseline: 1.0879x; 1.0063x over previous
//
#include <hip/hip_runtime.h>

#define GWG 256      // workgroups (1 per CU)
#define BTH 768      // threads per WG (12 waves)
#define WROW 2052    // LDS row pitch for Wih1 (bf16 elems)
#define LDSZ 141888
#define TB   0x5AB00001   // tag base: step t posts tag TB+t

typedef float f4v __attribute__((ext_vector_type(4)));

// ---------- helpers ----------
__device__ __forceinline__ unsigned short b16(float f) {   // f32 -> bf16 (RNE)
  union { float f; unsigned int i; } z; z.f = f;
  unsigned int r = z.i + 0x7fffu + ((z.i >> 16) & 1u);
  return (unsigned short)(r >> 16);
}
__device__ __forceinline__ float bup(unsigned short u) {
  union { unsigned int i; float f; } z; z.i = ((unsigned int)u) << 16; return z.f;
}
__device__ __forceinline__ float blo(unsigned int p) {
  union { unsigned int i; float f; } z; z.i = p << 16; return z.f;
}
__device__ __forceinline__ float bhi(unsigned int p) {
  union { unsigned int i; float f; } z; z.i = p & 0xffff0000u; return z.f;
}
__device__ __forceinline__ float sigm(float x) { return 1.f / (1.f + expf(-x)); }

__device__ __forceinline__ void stG(float* p2, f4v v) {
  asm volatile("global_store_dwordx4 %0, %1, off sc0 sc1" :: "v"(p2), "v"(v) : "memory");
}

// wave-0 gather of h mailbox (one replica): 64 lanes x 8 chunks -> f32 LDS
__device__ __forceinline__ void pollH(const float* mb, int tag, float* lH) {
  const int L = threadIdx.x;                 // caller guarantees < 64
  const float* base = mb + L * 4;
  f4v v[8];
  for (;;) {
#pragma unroll
    for (int s = 0; s < 8; ++s)
      asm volatile("global_load_dwordx4 %0, %1, off sc0 sc1"
                   : "=v"(v[s]) : "v"(base + s * 256) : "memory");
    asm volatile("s_waitcnt vmcnt(0)" ::: "memory");
    __builtin_amdgcn_sched_barrier(0);
    bool ok = true;
#pragma unroll
    for (int s = 0; s < 8; ++s) ok &= (__float_as_int(v[s][3]) == tag);
    if (__all(ok)) break;
    __builtin_amdgcn_s_sleep(1);
  }
#pragma unroll
  for (int s = 0; s < 8; ++s) {
    int c = s * 64 + L;
    unsigned u0 = __float_as_uint(v[s][0]);
    unsigned u1 = __float_as_uint(v[s][1]);
    f4v hw; hw[0] = blo(u0); hw[1] = bhi(u0); hw[2] = blo(u1); hw[3] = bhi(u1);
    *(f4v*)&lH[c * 4] = hw;                  // f32x4, b128 store
  }
}

// wave-0 gather of y mailbox (512 one-row chunks {y, e, -, tag}); returns lse (all lanes)
__device__ __forceinline__ float pollYE(const float* mb, int tag, float* lY) {
  const int L = threadIdx.x;
  const float* base = mb + L * 4;
  f4v v[8];
  for (;;) {
#pragma unroll
    for (int s = 0; s < 8; ++s)
      asm volatile("global_load_dwordx4 %0, %1, off sc0 sc1"
                   : "=v"(v[s]) : "v"(base + s * 256) : "memory");
    asm volatile("s_waitcnt vmcnt(0)" ::: "memory");
    __builtin_amdgcn_sched_barrier(0);
    bool ok = true;
#pragma unroll
    for (int s = 0; s < 8; ++s) ok &= (__float_as_int(v[s][3]) == tag);
    if (__all(ok)) break;
    __builtin_amdgcn_s_sleep(1);
  }
  float es = 0.f;
#pragma unroll
  for (int s = 0; s < 8; ++s) {
    int c = s * 64 + L;
    lY[c] = v[s][0];
    es += v[s][1];
  }
#pragma unroll
  for (int d = 1; d < 64; d <<= 1) es += __shfl_xor(es, d);
  return logf(es);
}

// ---------- pre-kernels ----------
__global__ __launch_bounds__(256) void prep(const float* __restrict__ bih0, const float* __restrict__ bhh0,
                                            const float* __restrict__ bih1, const float* __restrict__ bhh1,
                                            float* __restrict__ b0, float* __restrict__ b1f) {
  int i = blockIdx.x * 256 + threadIdx.x;
  if (i < 8192) { b0[i] = bih0[i] + bhh0[i]; b1f[i] = bih1[i] + bhh1[i]; }
}

__global__ __launch_bounds__(256) void transpose_wx(const float* __restrict__ Wih0, float* __restrict__ WxT) {
  int idx = blockIdx.x * 256 + threadIdx.x;          // 360*8192 total
  int r = idx & 8191, k = idx >> 13;
  WxT[(size_t)k * 8192 + r] = Wih0[(size_t)r * 424 + k];
}

// gates_x = inputVecs @ Wx^T + b0, bf16, COMPACT rows {i,g,o} -> [t][6144]
__global__ __launch_bounds__(256) void gemm_gx(const float* __restrict__ inV, const float* __restrict__ WxT,
                                               const float* __restrict__ b0, unsigned short* __restrict__ gxb) {
  __shared__ float lin[32 * 360];
  int t0 = blockIdx.x * 32;
  int by = blockIdx.y;                 // 0..23
  int ry = by >> 3;                    // 0,1,2  (compact gate)
  int gatey = ry + (ry ? 1 : 0);       // {0,2,3}
  int r  = gatey * 2048 + (by & 7) * 256 + threadIdx.x;   // original row (weights/bias)
  int cr = ry    * 2048 + (by & 7) * 256 + threadIdx.x;   // compact row (output)
  for (int i = threadIdx.x; i < 32 * 360; i += 256) lin[i] = inV[(size_t)t0 * 360 + i];
  __syncthreads();
  float b = b0[r];
  float acc[32];
#pragma unroll
  for (int tt = 0; tt < 32; ++tt) acc[tt] = b;
  for (int k = 0; k < 360; k += 4) {
    float w0 = WxT[(size_t)(k + 0) * 8192 + r];
    float w1 = WxT[(size_t)(k + 1) * 8192 + r];
    float w2 = WxT[(size_t)(k + 2) * 8192 + r];
    float w3 = WxT[(size_t)(k + 3) * 8192 + r];
#pragma unroll
    for (int tt = 0; tt < 32; ++tt) {
      float4 l = *reinterpret_cast<const float4*>(&lin[tt * 360 + k]);
      acc[tt] = fmaf(w0, l.x, fmaf(w1, l.y, fmaf(w2, l.z, fmaf(w3, l.w, acc[tt]))));
    }
  }
  for (int tt = 0; tt < 32; ++tt) gxb[(size_t)(t0 + tt) * 6144 + cr] = b16(acc[tt]);
}

// Wcomb = We @ Wmap, compact igo rows [6144][512], bf16
__global__ __launch_bounds__(256) void wcomb_k(const float* __restrict__ Wih0, const float* __restrict__ Wmap,
                                               unsigned short* __restrict__ wcomb) {
  __shared__ float lwe[64];
  int cr = blockIdx.x;                               // compact row 0..6143
  int orig = cr + (cr >= 2048 ? 2048 : 0);           // gate {0,2,3}
  if (threadIdx.x < 64) lwe[threadIdx.x] = Wih0[(size_t)orig * 424 + 360 + threadIdx.x];
  __syncthreads();
  int c = threadIdx.x;
  float a0 = 0.f, a1 = 0.f;
  for (int e = 0; e < 64; ++e) {
    float w = lwe[e];
    a0 = fmaf(w, Wmap[e * 512 + c], a0);
    a1 = fmaf(w, Wmap[e * 512 + c + 256], a1);
  }
  wcomb[(size_t)cr * 512 + c] = b16(a0);
  wcomb[(size_t)cr * 512 + c + 256] = b16(a1);
}

// rs = rowsum(Wcomb_bf16); bcomb = We@bmap; g0c = We@embed0   (compact [6144])
__global__ __launch_bounds__(256) void rsk(const unsigned short* __restrict__ wcomb,
                                           const float* __restrict__ Wih0,
                                           const float* __restrict__ bmap, const float* __restrict__ emb0,
                                           float* __restrict__ rs, float* __restrict__ bcomb,
                                           float* __restrict__ g0c) {
  int cr = blockIdx.x * 256 + threadIdx.x;
  if (cr >= 6144) return;
  int orig = cr + (cr >= 2048 ? 2048 : 0);
  float s = 0.f;
  for (int k = 0; k < 512; ++k) s += bup(wcomb[(size_t)cr * 512 + k]);
  float bc = 0.f, g0 = 0.f;
  for (int e = 0; e < 64; ++e) {
    float w = Wih0[(size_t)orig * 424 + 360 + e];
    bc = fmaf(w, bmap[e], bc);
    g0 = fmaf(w, emb0[e], g0);
  }
  rs[cr] = s; bcomb[cr] = bc; g0c[cr] = g0;
}

// ---------- persistent scan kernel ----------
struct KP {
  const float* Wih1; const float* Wlin; const float* blin; const float* b1f;
  const unsigned short* gxb; const unsigned short* wcomb;
  const float* rs; const float* bcomb; const float* g0c;
  float* mb_h0; float* mb_h1; float* mb_y;     // 8-replica tagged mailboxes
  float* out;
};

__global__ __launch_bounds__(BTH) void lstm_seq(KP p) {
  extern __shared__ __align__(16) char smem[];
  unsigned short* lW1  = (unsigned short*)smem;                 // 24 x WROW (Wih1 slice)  98,496
  unsigned short* lWl  = (unsigned short*)(smem + 98496);       // 2 x 2048  (Wlin rows)    8,192
  unsigned short* lWcb = (unsigned short*)(smem + 106688);      // 24 x 512  (Wcomb slice) 24,576
  float* lH  = (float*)(smem + 131264);                         // 2048 f32 (h gather)      8,192
  float* lY  = (float*)(smem + 139456);                         // 512 f32                  2,048
  float* lRA = (float*)(smem + 141504);                         // 24 (fold + gx + bc)
  float* lRS = (float*)(smem + 141632);                         // 24 (rs, static)
  float* lR  = (float*)(smem + 141760);                         // 24 (layer-1 pre-acts)

  const int w = blockIdx.x, tid = threadIdx.x;
  const int rl = tid >> 5;          // 0..23 gate-row
  const int l32 = tid & 31;
  const int g3 = rl >> 3;                   // 0,1,2 (i,g,o compact)
  const int gate = g3 + (g3 ? 1 : 0);       // {0,2,3} original layout
  const int gr  = w * 8 + (rl & 7) + 2048 * gate;   // original-space (Wih1, b1f)
  const int crt = w * 8 + (rl & 7) + 2048 * g3;     // compact (gxb, wcomb, rs, bcomb, g0c)
  const int rep = w & 7;                            // this consumer's replica
  const int wv  = tid >> 6;                         // wave id
  const int L64 = tid & 63;

  // ---- stage weights into LDS (once) ----
  for (int r2 = 0; r2 < 24; ++r2) {
    int gg = r2 >> 3; int grr = w * 8 + (r2 & 7) + 2048 * (gg + (gg ? 1 : 0));
    const float* src = p.Wih1 + (size_t)grr * 2048;
    for (int i = tid; i < 2048; i += BTH) lW1[r2 * WROW + i] = b16(src[i]);
  }
  for (int i = tid; i < 24 * 512; i += BTH) {
    int r2 = i >> 9, k = i & 511;
    int crr = w * 8 + (r2 & 7) + 2048 * (r2 >> 3);
    lWcb[r2 * 512 + k] = p.wcomb[(size_t)crr * 512 + k];
  }
  for (int i = tid; i < 2 * 2048; i += BTH) {
    int q = i >> 11, k = i & 2047;
    lWl[i] = b16(p.Wlin[(size_t)(w * 2 + q) * 2048 + k]);
  }
  const float b1r  = p.b1f[gr];
  const float rs_r = p.rs[crt], bc_r = p.bcomb[crt], g0_r = p.g0c[crt];
  const float blr  = (wv < 2) ? p.blin[w * 2 + wv] : 0.f;
  unsigned short gxu = p.gxb[crt];                 // gx for t=0
  if (l32 == 0) lRS[rl] = rs_r;
  __syncthreads();

  for (int t = 0; t < 4096; ++t) {
    const int tagt = TB + t;
    const unsigned short gxu_n = p.gxb[(size_t)(t < 4095 ? t + 1 : t) * 6144 + crt];
    float lse = 0.f;                                // valid in wave 0
    // ============ phase 1: gather y(t-1)+lse [wave0], Wcomb fold ============
    if (t > 0) {
      if (tid < 64) lse = pollYE(p.mb_y + rep * 2048, tagt - 1, lY);
      __syncthreads();                                         // S1 (lY ready)
      float acc = 0.f;
#pragma unroll
      for (int j = 0; j < 8; ++j) {
        int k = 2 * l32 + 64 * j;
        unsigned uwp = *(const unsigned*)&lWcb[rl * 512 + k];
        float2 yv2 = *(const float2*)&lY[k];
        acc = fmaf(blo(uwp), yv2.x, fmaf(bhi(uwp), yv2.y, acc));
      }
      acc += __shfl_xor(acc, 1); acc += __shfl_xor(acc, 2); acc += __shfl_xor(acc, 4);
      acc += __shfl_xor(acc, 8); acc += __shfl_xor(acc, 16);
      if (l32 == 0) lRA[rl] = bup(gxu) + acc + bc_r;
    } else {
      if (l32 == 0) lRA[rl] = bup(gxu) + g0_r;
    }
    __syncthreads();                                           // S3 (lRA ready)
    // wave0: cell -> h0 (lanes 0-7), pack, post to 8 replicas (lanes 0-15)
    if (tid < 16) {
      unsigned hb = 0u;
      if (tid < 8) {
        float pi = lRA[tid]      - lse * lRS[tid];
        float pg = lRA[8 + tid]  - lse * lRS[8 + tid];
        float po = lRA[16 + tid] - lse * lRS[16 + tid];
        float cc = sigm(pi) * tanhf(pg);
        hb = (unsigned)b16(sigm(po) * tanhf(cc));
      }
      int cpar = tid & 1;
      unsigned a0 = __shfl(hb, cpar * 4 + 0);
      unsigned a1 = __shfl(hb, cpar * 4 + 1);
      unsigned a2 = __shfl(hb, cpar * 4 + 2);
      unsigned a3 = __shfl(hb, cpar * 4 + 3);
      f4v c;
      c[0] = __uint_as_float(a0 | (a1 << 16));
      c[1] = __uint_as_float(a2 | (a3 << 16));
      c[2] = 0.f; c[3] = __int_as_float(tagt);
      stG(p.mb_h0 + (tid >> 1) * 2048 + (w * 2 + cpar) * 4, c);
    }
    // ============ phase 2: gather h0 [wave0], Wih1 matvec ============
    if (tid < 64) pollH(p.mb_h0 + rep * 2048, tagt, lH);
    __syncthreads();                                           // S5 (lH = h0)
    {
      float acc = 0.f;
      const unsigned short* wr = lW1 + rl * WROW;
#pragma unroll 4
      for (int mm = 0; mm < 16; ++mm) {
        int k = l32 * 4 + mm * 128;
        ushort4 uw = *(const ushort4*)&wr[k];
        float4 hv = *(const float4*)&lH[k];
        acc = fmaf(bup(uw.x), hv.x, acc);
        acc = fmaf(bup(uw.y), hv.y, acc);
        acc = fmaf(bup(uw.z), hv.z, acc);
        acc = fmaf(bup(uw.w), hv.w, acc);
      }
      acc += __shfl_xor(acc, 1); acc += __shfl_xor(acc, 2); acc += __shfl_xor(acc, 4);
      acc += __shfl_xor(acc, 8); acc += __shfl_xor(acc, 16);
      if (l32 == 0) lR[rl] = acc + b1r;
    }
    __syncthreads();                                           // S6 (lR ready)
    // wave0: cell -> h1, post to 8 replicas
    if (tid < 16) {
      unsigned hb = 0u;
      if (tid < 8) {
        float cc = sigm(lR[tid]) * tanhf(lR[8 + tid]);
        hb = (unsigned)b16(sigm(lR[16 + tid]) * tanhf(cc));
      }
      int cpar = tid & 1;
      unsigned a0 = __shfl(hb, cpar * 4 + 0);
      unsigned a1 = __shfl(hb, cpar * 4 + 1);
      unsigned a2 = __shfl(hb, cpar * 4 + 2);
      unsigned a3 = __shfl(hb, cpar * 4 + 3);
      f4v c;
      c[0] = __uint_as_float(a0 | (a1 << 16));
      c[1] = __uint_as_float(a2 | (a3 << 16));
      c[2] = 0.f; c[3] = __int_as_float(tagt);
      stG(p.mb_h1 + (tid >> 1) * 2048 + (w * 2 + cpar) * 4, c);
    }
    // ============ phase 3: gather h1 [wave0], per-wave y rows, post {y,e} ============
    if (tid < 64) pollH(p.mb_h1 + rep * 2048, tagt, lH);
    __syncthreads();                                           // S8 (lH = h1)
    if (wv < 2) {
      float a = 0.f;
#pragma unroll
      for (int i = 0; i < 8; ++i) {
        int k = L64 * 4 + i * 256;
        ushort4 uw = *(const ushort4*)&lWl[wv * 2048 + k];
        float4 hv = *(const float4*)&lH[k];
        a = fmaf(bup(uw.x), hv.x, fmaf(bup(uw.y), hv.y,
              fmaf(bup(uw.z), hv.z, fmaf(bup(uw.w), hv.w, a))));
      }
#pragma unroll
      for (int d = 1; d < 64; d <<= 1) a += __shfl_xor(a, d);   // sum in all lanes
      float y = a + blr;
      float e = expf(y);
      if (L64 < 8) {
        f4v c; c[0] = y; c[1] = e; c[2] = 0.f; c[3] = __int_as_float(tagt);
        stG(p.mb_y + L64 * 2048 + (w * 2 + wv) * 4, c);
      }
      if (L64 == 0) p.out[(size_t)t * 512 + w * 2 + wv] = y;
    }
    gxu = gxu_n;
  }
}

// ---------- host ----------
extern "C" void kernel_launch(void* const* d_in, const int* in_sizes, int n_in,
                              void* d_out, int out_size, void* d_ws, size_t ws_size,
                              hipStream_t stream) {
  const float* inV  = (const float*)d_in[0];
  const float* Wih0 = (const float*)d_in[1];
  const float* bih0 = (const float*)d_in[2];
  const float* bhh0 = (const float*)d_in[3];
  const float* Wih1 = (const float*)d_in[4];
  const float* bih1 = (const float*)d_in[5];
  const float* bhh1 = (const float*)d_in[6];
  const float* Wlin = (const float*)d_in[7];
  const float* blin = (const float*)d_in[8];
  const float* Wmap = (const float*)d_in[9];
  const float* bmap = (const float*)d_in[10];
  const float* emb0 = (const float*)d_in[11];

  char* ws = (char*)d_ws;
  unsigned short* gxb   = (unsigned short*)(ws);             // 4096*6144*2 = 50,331,648
  float*          WxT   = (float*)(ws + 50331648);           // 11,796,480 (dead after gemm_gx)
  unsigned short* wcomb = (unsigned short*)(ws + 50331648);  // 6,291,456 (aliases WxT, written after)
  float* b0    = (float*)(ws + 62128128);                    // 32 KB
  float* b1f   = (float*)(ws + 62160896);                    // 32 KB
  float* mb_h0 = (float*)(ws + 62193664);                    // 64 KB (8 replicas x 512 x 16B)
  float* mb_h1 = (float*)(ws + 62259200);                    // 64 KB
  float* mb_y  = (float*)(ws + 62324736);                    // 64 KB (8 replicas x 512 x 16B)
  float* rs    = (float*)(ws + 62390272);                    // 24 KB
  float* bcomb = (float*)(ws + 62414848);                    // 24 KB
  float* g0c   = (float*)(ws + 62439424);                    // 24 KB
  float* out   = (float*)d_out;

  prep<<<32, 256, 0, stream>>>(bih0, bhh0, bih1, bhh1, b0, b1f);
  transpose_wx<<<11520, 256, 0, stream>>>(Wih0, WxT);
  gemm_gx<<<dim3(128, 24), 256, 0, stream>>>(inV, WxT, b0, gxb);
  wcomb_k<<<6144, 256, 0, stream>>>(Wih0, Wmap, wcomb);      // overwrites WxT region (now dead)
  rsk<<<24, 256, 0, stream>>>(wcomb, Wih0, bmap, emb0, rs, bcomb, g0c);

  hipFuncSetAttribute(reinterpret_cast<const void*>(lstm_seq),
                      hipFuncAttributeMaxDynamicSharedMemorySize, LDSZ);
  KP p{Wih1, Wlin, blin, b1f, gxb, wcomb, rs, bcomb, g0c, mb_h0, mb_h1, mb_y, out};
  void* args[] = { (void*)&p };
  hipError_t e = hipLaunchCooperativeKernel(reinterpret_cast<void*>(&lstm_seq),
                                            dim3(GWG), dim3(BTH), args, LDSZ, stream);
  if (e != hipSuccess) {
    lstm_seq<<<GWG, BTH, LDSZ, stream>>>(p);
  }
}